// Round 9
// baseline (3865.851 us; speedup 1.0000x reference)
//
#include <hip/hip_runtime.h>
#include <cstdint>
#include <cstddef>

// LayerNormLSTM on MI355X.
// Phase 0: fp32->bf16 conversion of x, Wi, Wh.
// Phase 1: Gpre = x @ Wi^T  (bf16 MFMA 16x16x32, 128x128 tiles).
// Phase 1.5: in-place row LN (scale=b1, shift=s1) over the 2048 gate dim.
// Phase 2: persistent recurrence, 64 wgs = 4 teams(16 samples) x 16 slices.
//   R12 = R8 (best measured: flag->payload, all-MALL) with the publish
//   de-serialized: instead of {vmcnt ack; __syncthreads; tid0 flag}, each
//   wave acks its own stores (vmcnt(0)) and bumps an LDS counter; the
//   8th-arriving wave posts the wg's flag immediately. Removes the S5
//   barrier drain + tid0 wakeup leg from every step's critical path.
//   Consumer protocol unchanged: narrow paced sweep {16 flags + 1 c-stat},
//   then ONE sc1 dwordx4 payload read. c-LN deferred into consumers (R5);
//   t=0 reads hx directly.

typedef float  f32x4 __attribute__((ext_vector_type(4)));
typedef __bf16 bf16x8 __attribute__((ext_vector_type(8)));
typedef unsigned int u32x4 __attribute__((ext_vector_type(4)));
typedef unsigned short u16x4 __attribute__((ext_vector_type(4)));

#define DEV __device__ __forceinline__

// agent-scope (MALL) 16B load, untracked by compiler -> manual waitcnt
#define LD4_AGENT(dst, p) asm volatile("global_load_dwordx4 %0, %1, off sc1" : "=v"(dst) : "v"(p))
#define VM0_FENCE() do{ asm volatile("s_waitcnt vmcnt(0)" ::: "memory"); \
                        __builtin_amdgcn_sched_barrier(0); }while(0)

DEV unsigned short f2b(float f){
  unsigned int u = __builtin_bit_cast(unsigned int, f);
  unsigned int r = (u + 0x7FFFu + ((u >> 16) & 1u)) >> 16;
  return (unsigned short)r;
}
DEV float b2f(unsigned short s){
  unsigned int u = ((unsigned int)s) << 16;
  return __builtin_bit_cast(float, u);
}
DEV float tanh_fast(float x){
  const float e = __expf(2.f * x);
  return 1.f - 2.f * __builtin_amdgcn_rcpf(e + 1.f);
}
DEV float sigmoid_fast(float x){
  return __builtin_amdgcn_rcpf(1.f + __expf(-x));
}

// ---------------- Phase 0: conversion ----------------
__global__ __launch_bounds__(256) void conv_bf16(const float* __restrict__ src,
                                                 unsigned short* __restrict__ dst,
                                                 int n4){
  int i = blockIdx.x * 256 + threadIdx.x;
  if (i >= n4) return;
  f32x4 v = ((const f32x4*)src)[i];
  u16x4 o;
  #pragma unroll
  for (int j = 0; j < 4; ++j) o[j] = f2b(v[j]);
  ((u16x4*)dst)[i] = o;
}

// ---------------- Phase 1: Gpre = Xb @ Wib^T ----------------
__global__ __launch_bounds__(256, 2) void gemm_gi(const unsigned short* __restrict__ Xb,
                                                  const unsigned short* __restrict__ Wib,
                                                  unsigned short* __restrict__ Gp){
  __shared__ unsigned short As[128 * 48];
  __shared__ unsigned short Bs[128 * 48];
  const int tid = threadIdx.x;
  const int m0 = blockIdx.x * 128;
  const int n0 = blockIdx.y * 128;
  const int w = tid >> 6, lane = tid & 63;
  const int lr = lane & 15, lq = lane >> 4;
  const int wm = (w & 1) * 64, wn = (w >> 1) * 64;
  const int sr = tid >> 2;
  const int sc = (tid & 3) * 8;
  const unsigned short* gx = Xb + (size_t)(m0 + sr) * 512 + sc;
  const unsigned short* gw = Wib + (size_t)(n0 + sr) * 512 + sc;
  f32x4 acc[4][4] = {};
  for (int kb = 0; kb < 16; ++kb){
    u32x4 a0 = *(const u32x4*)(gx + kb * 32);
    u32x4 a1 = *(const u32x4*)(gx + 64 * 512 + kb * 32);
    u32x4 b0 = *(const u32x4*)(gw + kb * 32);
    u32x4 b1 = *(const u32x4*)(gw + 64 * 512 + kb * 32);
    __syncthreads();
    *(u32x4*)&As[sr * 48 + sc] = a0;
    *(u32x4*)&As[(sr + 64) * 48 + sc] = a1;
    *(u32x4*)&Bs[sr * 48 + sc] = b0;
    *(u32x4*)&Bs[(sr + 64) * 48 + sc] = b1;
    __syncthreads();
    bf16x8 af[4], bfv[4];
    #pragma unroll
    for (int mi = 0; mi < 4; ++mi) af[mi] = *(const bf16x8*)&As[(wm + mi * 16 + lr) * 48 + lq * 8];
    #pragma unroll
    for (int ni = 0; ni < 4; ++ni) bfv[ni] = *(const bf16x8*)&Bs[(wn + ni * 16 + lr) * 48 + lq * 8];
    #pragma unroll
    for (int mi = 0; mi < 4; ++mi)
      #pragma unroll
      for (int ni = 0; ni < 4; ++ni)
        acc[mi][ni] = __builtin_amdgcn_mfma_f32_16x16x32_bf16(af[mi], bfv[ni], acc[mi][ni], 0, 0, 0);
  }
  #pragma unroll
  for (int mi = 0; mi < 4; ++mi){
    const int rowb = m0 + wm + mi * 16 + lq * 4;
    #pragma unroll
    for (int ni = 0; ni < 4; ++ni){
      const int col = n0 + wn + ni * 16 + lr;
      #pragma unroll
      for (int r = 0; r < 4; ++r)
        Gp[(size_t)(rowb + r) * 2048 + col] = f2b(acc[mi][ni][r]);
    }
  }
}

// ---------------- Phase 1.5: row LN (scale=b1, shift=s1) ----------------
__global__ __launch_bounds__(256) void ln_rows(unsigned short* __restrict__ G,
                                               const float* __restrict__ b1,
                                               const float* __restrict__ s1){
  const int row = blockIdx.x;
  const int tid = threadIdx.x;
  unsigned short* rp = G + (size_t)row * 2048 + tid * 8;
  u32x4 raw = *(const u32x4*)rp;
  float x[8];
  #pragma unroll
  for (int j = 0; j < 8; ++j){
    unsigned int word = raw[j >> 1];
    unsigned short us = (j & 1) ? (unsigned short)(word >> 16) : (unsigned short)(word & 0xFFFF);
    x[j] = b2f(us);
  }
  float s = 0.f, q = 0.f;
  #pragma unroll
  for (int j = 0; j < 8; ++j){ s += x[j]; q += x[j] * x[j]; }
  #pragma unroll
  for (int o = 1; o < 64; o <<= 1){ s += __shfl_xor(s, o); q += __shfl_xor(q, o); }
  __shared__ float ps[4][2];
  const int wv = tid >> 6;
  if ((tid & 63) == 0){ ps[wv][0] = s; ps[wv][1] = q; }
  __syncthreads();
  s = ps[0][0] + ps[1][0] + ps[2][0] + ps[3][0];
  q = ps[0][1] + ps[1][1] + ps[2][1] + ps[3][1];
  const float mu = s * (1.f / 2048.f);
  const float inv = rsqrtf((q - s * mu) + 1e-5f);
  const float* b1p = b1 + tid * 8;
  const float* s1p = s1 + tid * 8;
  u32x4 outw;
  #pragma unroll
  for (int j = 0; j < 4; ++j){
    float y0 = b1p[2 * j]     * ((x[2 * j]     - mu) * inv) + s1p[2 * j];
    float y1 = b1p[2 * j + 1] * ((x[2 * j + 1] - mu) * inv) + s1p[2 * j + 1];
    outw[j] = (unsigned int)f2b(y0) | ((unsigned int)f2b(y1) << 16);
  }
  *(u32x4*)rp = outw;
}

// ---------------- Phase 2: persistent recurrence ----------------
__global__ __launch_bounds__(512, 2) void lstm_rec(
    const unsigned short* __restrict__ Gi,   // [32768][2048] bf16, post-LN gi
    const unsigned short* __restrict__ Whb,  // [2048][512] bf16
    const float* __restrict__ bias,
    const float* __restrict__ b2, const float* __restrict__ s2,
    const float* __restrict__ b3, const float* __restrict__ s3,
    const float* __restrict__ hx,            // [64][512] f32 (t=0 h)
    const float* __restrict__ cx,
    unsigned int* __restrict__ hbuf,         // [2][64][512] u32 {o|cc} bf16, UNTAGGED
    unsigned long long* __restrict__ pF,     // [2][4][16] flag u64 = step tag, zeroed
    unsigned long long* __restrict__ pA,     // [2][4][16][32] tagged u64, zeroed
    unsigned long long* __restrict__ pCs,    // [2][4][16][32] tagged u64, zeroed
    float* __restrict__ out){
  const int tid = threadIdx.x;
  const int tm = (blockIdx.x >> 1) & 3;                  // team
  const int ks = ((blockIdx.x >> 3) << 1) | (blockIdx.x & 1);  // slice
  const int w = tid >> 6;
  const int lane = tid & 63;
  const int lr = lane & 15, lq = lane >> 4;

  // gate-wave constants: wave w owns gate rows type*512 + ks*32 + jloc
  const int type = w >> 1;
  const int jloc = (w & 1) * 16 + lr;
  const int row_g = type * 512 + ks * 32 + jloc;
  const float b2r = b2[row_g];
  const float sbr = s2[row_g] + bias[row_g];

  // Wh B-fragments in registers
  bf16x8 bfr[16];
  {
    const unsigned short* wr = Whb + (size_t)row_g * 512 + lq * 8;
    #pragma unroll
    for (int kk = 0; kk < 16; ++kk) bfr[kk] = *(const bf16x8*)(wr + kk * 32);
  }

  // c-phase constants
  const int cs = tid >> 5;                 // team sample 0..15 (== psmp below)
  const int cj = tid & 31;                 // col within slice
  const int hcol = ks * 32 + cj;
  const int bidx = tm * 16 + cs;
  float c_val = cx[(size_t)bidx * 512 + hcol];
  const float b3j = b3[hcol], s3j = s3[hcol];

  // poll coords: wave w covers team samples 2w, 2w+1
  const int psmp = 2 * w + (lane >> 5);    // 0..15 (equals this thread's cs)
  const int pidx = lane & 31;
  const int pl_slice = (lane >> 1) & 15;
  const int pl_kind  = lane & 1;

  // register-cache b3/s3 for reconstruction cols: c = 4*pidx + 128*q + j
  float b3c[16], s3c[16];
  #pragma unroll
  for (int q = 0; q < 4; ++q)
    #pragma unroll
    for (int j = 0; j < 4; ++j){
      const int c = 4 * pidx + 128 * q + j;
      b3c[4 * q + j] = b3[c];
      s3c[4 * q + j] = s3[c];
    }

  __shared__ unsigned short hlds[16 * 520];
  __shared__ float act[4][32][17];
  __shared__ float redA[8][16][2];
  __shared__ float stAl[16][2];
  __shared__ unsigned int lcnt;            // publish counter (monotone, no reset)
  if (tid == 0) lcnt = 0u;

  float cc_own = 0.f, o_own = 0.f;

  for (int t = 0; t < 512; ++t){
    // gi prefetch (in flight during the flag poll)
    float giv[4];
    #pragma unroll
    for (int r = 0; r < 4; ++r){
      const int b = tm * 16 + lq * 4 + r;
      giv[r] = b2f(Gi[((size_t)b * 512 + t) * 2048 + row_g]);
    }

    if (t == 0){
      // read hx directly (kernel argument; ready at launch, no sync needed)
      const float* hr = hx + (size_t)(tm * 16 + psmp) * 512;
      #pragma unroll
      for (int q = 0; q < 4; ++q){
        f32x4 hv4 = *(const f32x4*)(hr + 4 * pidx + 128 * q);
        unsigned long long pk = 0;
        #pragma unroll
        for (int j = 0; j < 4; ++j)
          pk |= (unsigned long long)f2b(hv4[j]) << (16 * j);
        *(unsigned long long*)&hlds[psmp * 520 + 4 * pidx + 128 * q] = pk;
      }
    } else {
      // ---- phase 1: cheap sweep {16 flags + 1 c-stat}, 2 loads/lane ----
      const unsigned int tg = (unsigned)t;
      const unsigned long long* fp = pF + (size_t)(t & 1) * 64 + tm * 16 + (lane & 15);
      const unsigned long long* sp =
          pCs + ((size_t)(t & 1) * 4 + tm) * 512 + pl_slice * 32 + psmp * 2 + pl_kind;
      unsigned long long sv;
      for (;;){
        unsigned long long fv = __hip_atomic_load(fp, __ATOMIC_RELAXED, __HIP_MEMORY_SCOPE_AGENT);
        sv = __hip_atomic_load(sp, __ATOMIC_RELAXED, __HIP_MEMORY_SCOPE_AGENT);
        bool ok = ((unsigned)fv == tg) & ((unsigned)(sv >> 32) == tg);
        if (__all((int)ok)) break;
        __builtin_amdgcn_s_sleep(1);
      }
      // ---- phase 2: read payload ONCE (in flight under the stat reduce) ----
      const unsigned int* hsrc =
          hbuf + (size_t)(t & 1) * 32768 + (size_t)(tm * 16 + psmp) * 512;
      u32x4 pay[4];
      #pragma unroll
      for (int q = 0; q < 4; ++q) LD4_AGENT(pay[q], hsrc + 4 * pidx + 128 * q);
      // c-stats: butterfly over 16 slices, then kind exchange
      float pv = __builtin_bit_cast(float, (unsigned)sv);
      #pragma unroll
      for (int o = 2; o < 32; o <<= 1) pv += __shfl_xor(pv, o);
      const float ov = __shfl_xor(pv, 1);
      const float S = pl_kind ? ov : pv;
      const float Q = pl_kind ? pv : ov;
      const float mu = S * (1.f / 512.f);
      const float inv = rsqrtf((Q - S * mu) + 1e-5f);
      // own carried state + previous step's out row (sample cs == psmp)
      c_val = b3j * ((cc_own - mu) * inv) + s3j;
      const float h_self = o_own * tanh_fast(c_val);
      out[((size_t)bidx * 512 + (t - 1)) * 512 + hcol] = h_self;
      VM0_FENCE();                     // payload arrived
      // reconstruct h(t) for sample psmp: 16 cols per lane
      #pragma unroll
      for (int q = 0; q < 4; ++q){
        unsigned long long pk = 0;
        #pragma unroll
        for (int j = 0; j < 4; ++j){
          const unsigned int v = pay[q][j];
          const float ccv = b2f((unsigned short)(v & 0xFFFF));
          const float oov = b2f((unsigned short)(v >> 16));
          const float h = oov * tanh_fast(b3c[4 * q + j] * ((ccv - mu) * inv) + s3c[4 * q + j]);
          pk |= (unsigned long long)f2b(h) << (16 * j);
        }
        *(unsigned long long*)&hlds[psmp * 520 + 4 * pidx + 128 * q] = pk;
      }
    }
    __syncthreads();                                   // S1

    // A-frags from LDS; MFMA over K=512
    f32x4 acc = {0.f, 0.f, 0.f, 0.f};
    #pragma unroll
    for (int kk = 0; kk < 16; ++kk){
      bf16x8 af = *(const bf16x8*)&hlds[lr * 520 + lq * 8 + kk * 32];
      acc = __builtin_amdgcn_mfma_f32_16x16x32_bf16(af, bfr[kk], acc, 0, 0, 0);
    }
    // per-sample partial (s,q) over this wave's 16 gate cols
    #pragma unroll
    for (int r = 0; r < 4; ++r){
      float s = acc[r], q = acc[r] * acc[r];
      #pragma unroll
      for (int o = 1; o < 16; o <<= 1){ s += __shfl_xor(s, o); q += __shfl_xor(q, o); }
      if (lr == 0){ redA[w][lq * 4 + r][0] = s; redA[w][lq * 4 + r][1] = q; }
    }
    __syncthreads();                                   // S2

    // ---- hop A: tagged partial store + direct all-wave poll ----
    unsigned long long* slotA = pA + ((size_t)(t & 1) * 4 + tm) * 512;  // [16][32] u64
    const unsigned int atag = (unsigned)(t + 1);
    if (w == 0 && lane < 32){
      const int smp = lane >> 1, kd = lane & 1;
      float Sp = 0.f;
      #pragma unroll
      for (int w2 = 0; w2 < 8; ++w2) Sp += redA[w2][smp][kd];
      const unsigned long long pvs = ((unsigned long long)atag << 32) |
          (unsigned long long)__builtin_bit_cast(unsigned int, Sp);
      __hip_atomic_store(slotA + (size_t)ks * 32 + lane, pvs,
                         __ATOMIC_RELAXED, __HIP_MEMORY_SCOPE_AGENT);
    }
    {
      const unsigned long long* ap = slotA + pl_slice * 32 + psmp * 2 + pl_kind;
      unsigned long long av;
      for (;;){
        av = __hip_atomic_load(ap, __ATOMIC_RELAXED, __HIP_MEMORY_SCOPE_AGENT);
        if (__all((int)((unsigned)(av >> 32) == atag))) break;
        __builtin_amdgcn_s_sleep(1);
      }
      float pv = __builtin_bit_cast(float, (unsigned)av);
      #pragma unroll
      for (int o = 2; o < 32; o <<= 1) pv += __shfl_xor(pv, o);  // sum 16 slices
      const float ov = __shfl_xor(pv, 1);
      const float S = pl_kind ? ov : pv;
      const float Q = pl_kind ? pv : ov;
      if ((lane & 31) == 0){
        const float mu = S * (1.f / 2048.f);
        stAl[psmp][0] = mu;
        stAl[psmp][1] = rsqrtf((Q - S * mu) + 1e-5f);
      }
    }
    __syncthreads();                                   // S3

    // gates + activations
    #pragma unroll
    for (int r = 0; r < 4; ++r){
      const int s0 = lq * 4 + r;
      const float nv = (acc[r] - stAl[s0][0]) * stAl[s0][1];
      const float gv = giv[r] + b2r * nv + sbr;
      float a;
      if (type == 2) a = tanh_fast(gv);
      else           a = sigmoid_fast(gv);
      act[type][jloc][s0] = a;
    }
    __syncthreads();                                   // S4

    // c-candidate; post UNTAGGED payload {o|cc} immediately
    const float i_g = act[0][cj][cs];
    const float f_g = act[1][cj][cs];
    const float g_g = act[2][cj][cs];
    const float o_g = act[3][cj][cs];
    const float cc = f_g * c_val + i_g * g_g;
    const unsigned int ntag = (unsigned)(t + 1);
    const size_t np = (size_t)((t + 1) & 1);
    {
      const unsigned int pv32 = (unsigned int)f2b(cc) | ((unsigned int)f2b(o_g) << 16);
      __hip_atomic_store(hbuf + np * 32768 + (size_t)bidx * 512 + hcol, pv32,
                         __ATOMIC_RELAXED, __HIP_MEMORY_SCOPE_AGENT);
    }
    // per-sample c-stats (32-lane in-wave reduce), then post
    float sC = cc, qC = cc * cc;
    #pragma unroll
    for (int o = 1; o < 32; o <<= 1){ sC += __shfl_xor(sC, o); qC += __shfl_xor(qC, o); }
    unsigned long long* slotC = pCs + (np * 4 + tm) * 512;  // [16][32] u64
    if ((lane & 31) < 2){
      const float v = (lane & 1) ? qC : sC;
      const unsigned long long pvs = ((unsigned long long)ntag << 32) |
          (unsigned long long)__builtin_bit_cast(unsigned int, v);
      __hip_atomic_store(slotC + (size_t)ks * 32 + cs * 2 + (lane & 1), pvs,
                         __ATOMIC_RELAXED, __HIP_MEMORY_SCOPE_AGENT);
    }
    // ---- publish: per-wave ack; 8th-arriving wave posts the flag ----
    VM0_FENCE();
    if (lane == 0){
      const unsigned old = atomicAdd(&lcnt, 1u);
      if (old == 8u * (unsigned)t + 7u)
        __hip_atomic_store(pF + np * 64 + tm * 16 + ks, (unsigned long long)ntag,
                           __ATOMIC_RELAXED, __HIP_MEMORY_SCOPE_AGENT);
    }
    cc_own = cc; o_own = o_g;
  }

  // epilogue: finish step-511 LN (tag 512, parity 0) and write tail outputs
  {
    const unsigned long long* sp =
        pCs + ((size_t)0 * 4 + tm) * 512 + pl_slice * 32 + psmp * 2 + pl_kind;
    unsigned long long sv;
    for (;;){
      sv = __hip_atomic_load(sp, __ATOMIC_RELAXED, __HIP_MEMORY_SCOPE_AGENT);
      if (__all((int)((unsigned)(sv >> 32) == 512u))) break;
      __builtin_amdgcn_s_sleep(2);
    }
    float pv = __builtin_bit_cast(float, (unsigned)sv);
    #pragma unroll
    for (int o = 2; o < 32; o <<= 1) pv += __shfl_xor(pv, o);
    const float ov = __shfl_xor(pv, 1);
    const float S = pl_kind ? ov : pv;
    const float Q = pl_kind ? pv : ov;
    const float mu = S * (1.f / 512.f);
    const float inv = rsqrtf((Q - S * mu) + 1e-5f);
    const float cn = b3j * ((cc_own - mu) * inv) + s3j;
    const float h = o_own * tanh_fast(cn);
    out[((size_t)bidx * 512 + 511) * 512 + hcol] = h;
    out[16777216u + (size_t)bidx * 512 + hcol] = h;
    out[16777216u + 32768u + (size_t)bidx * 512 + hcol] = cn;
  }
}

extern "C" void kernel_launch(void* const* d_in, const int* in_sizes, int n_in,
                              void* d_out, int out_size, void* d_ws, size_t ws_size,
                              hipStream_t stream){
  (void)in_sizes; (void)n_in; (void)out_size; (void)ws_size;
  const float* x    = (const float*)d_in[0];
  const float* hx   = (const float*)d_in[1];
  const float* cx   = (const float*)d_in[2];
  const float* Wi   = (const float*)d_in[3];
  const float* Wh   = (const float*)d_in[4];
  const float* bias = (const float*)d_in[5];
  const float* b1   = (const float*)d_in[6];
  const float* b2   = (const float*)d_in[7];
  const float* b3   = (const float*)d_in[8];
  const float* s1   = (const float*)d_in[9];
  const float* s2   = (const float*)d_in[10];
  const float* s3   = (const float*)d_in[11];
  float* out = (float*)d_out;
  char* ws = (char*)d_ws;

  unsigned short*     xb   = (unsigned short*)(ws);                 // 33,554,432
  unsigned short*     wib  = (unsigned short*)(ws + 33554432);      //  2,097,152
  unsigned short*     whb  = (unsigned short*)(ws + 35651584);      //  2,097,152
  unsigned short*     gp   = (unsigned short*)(ws + 37748736);      // 134,217,728
  unsigned int*       hbuf = (unsigned int*)(ws + 171966464);       //    262,144  [2][64][512] u32
  unsigned long long* pF   = (unsigned long long*)(ws + 172228608); //      1,024 (region reserved)
  unsigned long long* pA   = (unsigned long long*)(ws + 172490752); //     32,768
  unsigned long long* pCs  = (unsigned long long*)(ws + 172523520); //     32,768

  // zero pF..pCs (contiguous 327,680 B). hbuf needs no init (flag-gated).
  hipMemsetAsync(pF, 0, 327680, stream);
  conv_bf16<<<16384, 256, 0, stream>>>(x,  xb,  4194304);
  conv_bf16<<<1024,  256, 0, stream>>>(Wi, wib, 262144);
  conv_bf16<<<1024,  256, 0, stream>>>(Wh, whb, 262144);
  gemm_gi<<<dim3(256, 16, 1), 256, 0, stream>>>(xb, wib, gp);
  ln_rows<<<32768, 256, 0, stream>>>(gp, b1, s1);
  lstm_rec<<<64, 512, 0, stream>>>(gp, whb, bias, b2, s2, b3, s3, hx, cx,
                                   hbuf, pF, pA, pCs, out);
}

// Round 10
// 3251.879 us; speedup vs baseline: 1.1888x; 1.1888x over previous
//
#include <hip/hip_runtime.h>
#include <cstdint>
#include <cstddef>

// LayerNormLSTM on MI355X.
// Phase 0: fp32->bf16 conversion of x, Wi, Wh.
// Phase 1: Gpre = x @ Wi^T  (bf16 MFMA 16x16x32, 128x128 tiles).
// Phase 1.5: in-place row LN (scale=b1, shift=s1) over the 2048 gate dim.
// Phase 2: persistent recurrence, 64 wgs = 4 teams(16 samples) x 16 slices.
//   R13 == R8 exactly (best measured lstm_rec: 2790us). Two-phase
//   flag->payload rendezvous: h payload {cc,o} stored UNTAGGED (u32/col);
//   each wg posts ONE tagged flag per step after a vmcnt(0)+barrier
//   write-ack. Consumers sweep only {16 flags + 1 c-stat} (2 loads/lane,
//   paced), then read the payload ONCE with sc1 dwordx4. c-LN deferred
//   into consumers (R5). Gate-LN stats (hop A): tagged-u64 1-load/lane
//   poll, s_sleep(2) paced. t=0 reads hx directly. All sync at MALL/agent
//   scope (sc0/L2-scope measured non-viable in R6/R9/R10).

typedef float  f32x4 __attribute__((ext_vector_type(4)));
typedef __bf16 bf16x8 __attribute__((ext_vector_type(8)));
typedef unsigned int u32x4 __attribute__((ext_vector_type(4)));
typedef unsigned short u16x4 __attribute__((ext_vector_type(4)));

#define DEV __device__ __forceinline__

// agent-scope (MALL) 16B load, untracked by compiler -> manual waitcnt
#define LD4_AGENT(dst, p) asm volatile("global_load_dwordx4 %0, %1, off sc1" : "=v"(dst) : "v"(p))
#define VM0_FENCE() do{ asm volatile("s_waitcnt vmcnt(0)" ::: "memory"); \
                        __builtin_amdgcn_sched_barrier(0); }while(0)

DEV unsigned short f2b(float f){
  unsigned int u = __builtin_bit_cast(unsigned int, f);
  unsigned int r = (u + 0x7FFFu + ((u >> 16) & 1u)) >> 16;
  return (unsigned short)r;
}
DEV float b2f(unsigned short s){
  unsigned int u = ((unsigned int)s) << 16;
  return __builtin_bit_cast(float, u);
}
DEV float tanh_fast(float x){
  const float e = __expf(2.f * x);
  return 1.f - 2.f * __builtin_amdgcn_rcpf(e + 1.f);
}
DEV float sigmoid_fast(float x){
  return __builtin_amdgcn_rcpf(1.f + __expf(-x));
}

// ---------------- Phase 0: conversion ----------------
__global__ __launch_bounds__(256) void conv_bf16(const float* __restrict__ src,
                                                 unsigned short* __restrict__ dst,
                                                 int n4){
  int i = blockIdx.x * 256 + threadIdx.x;
  if (i >= n4) return;
  f32x4 v = ((const f32x4*)src)[i];
  u16x4 o;
  #pragma unroll
  for (int j = 0; j < 4; ++j) o[j] = f2b(v[j]);
  ((u16x4*)dst)[i] = o;
}

// ---------------- Phase 1: Gpre = Xb @ Wib^T ----------------
__global__ __launch_bounds__(256, 2) void gemm_gi(const unsigned short* __restrict__ Xb,
                                                  const unsigned short* __restrict__ Wib,
                                                  unsigned short* __restrict__ Gp){
  __shared__ unsigned short As[128 * 48];
  __shared__ unsigned short Bs[128 * 48];
  const int tid = threadIdx.x;
  const int m0 = blockIdx.x * 128;
  const int n0 = blockIdx.y * 128;
  const int w = tid >> 6, lane = tid & 63;
  const int lr = lane & 15, lq = lane >> 4;
  const int wm = (w & 1) * 64, wn = (w >> 1) * 64;
  const int sr = tid >> 2;
  const int sc = (tid & 3) * 8;
  const unsigned short* gx = Xb + (size_t)(m0 + sr) * 512 + sc;
  const unsigned short* gw = Wib + (size_t)(n0 + sr) * 512 + sc;
  f32x4 acc[4][4] = {};
  for (int kb = 0; kb < 16; ++kb){
    u32x4 a0 = *(const u32x4*)(gx + kb * 32);
    u32x4 a1 = *(const u32x4*)(gx + 64 * 512 + kb * 32);
    u32x4 b0 = *(const u32x4*)(gw + kb * 32);
    u32x4 b1 = *(const u32x4*)(gw + 64 * 512 + kb * 32);
    __syncthreads();
    *(u32x4*)&As[sr * 48 + sc] = a0;
    *(u32x4*)&As[(sr + 64) * 48 + sc] = a1;
    *(u32x4*)&Bs[sr * 48 + sc] = b0;
    *(u32x4*)&Bs[(sr + 64) * 48 + sc] = b1;
    __syncthreads();
    bf16x8 af[4], bfv[4];
    #pragma unroll
    for (int mi = 0; mi < 4; ++mi) af[mi] = *(const bf16x8*)&As[(wm + mi * 16 + lr) * 48 + lq * 8];
    #pragma unroll
    for (int ni = 0; ni < 4; ++ni) bfv[ni] = *(const bf16x8*)&Bs[(wn + ni * 16 + lr) * 48 + lq * 8];
    #pragma unroll
    for (int mi = 0; mi < 4; ++mi)
      #pragma unroll
      for (int ni = 0; ni < 4; ++ni)
        acc[mi][ni] = __builtin_amdgcn_mfma_f32_16x16x32_bf16(af[mi], bfv[ni], acc[mi][ni], 0, 0, 0);
  }
  #pragma unroll
  for (int mi = 0; mi < 4; ++mi){
    const int rowb = m0 + wm + mi * 16 + lq * 4;
    #pragma unroll
    for (int ni = 0; ni < 4; ++ni){
      const int col = n0 + wn + ni * 16 + lr;
      #pragma unroll
      for (int r = 0; r < 4; ++r)
        Gp[(size_t)(rowb + r) * 2048 + col] = f2b(acc[mi][ni][r]);
    }
  }
}

// ---------------- Phase 1.5: row LN (scale=b1, shift=s1) ----------------
__global__ __launch_bounds__(256) void ln_rows(unsigned short* __restrict__ G,
                                               const float* __restrict__ b1,
                                               const float* __restrict__ s1){
  const int row = blockIdx.x;
  const int tid = threadIdx.x;
  unsigned short* rp = G + (size_t)row * 2048 + tid * 8;
  u32x4 raw = *(const u32x4*)rp;
  float x[8];
  #pragma unroll
  for (int j = 0; j < 8; ++j){
    unsigned int word = raw[j >> 1];
    unsigned short us = (j & 1) ? (unsigned short)(word >> 16) : (unsigned short)(word & 0xFFFF);
    x[j] = b2f(us);
  }
  float s = 0.f, q = 0.f;
  #pragma unroll
  for (int j = 0; j < 8; ++j){ s += x[j]; q += x[j] * x[j]; }
  #pragma unroll
  for (int o = 1; o < 64; o <<= 1){ s += __shfl_xor(s, o); q += __shfl_xor(q, o); }
  __shared__ float ps[4][2];
  const int wv = tid >> 6;
  if ((tid & 63) == 0){ ps[wv][0] = s; ps[wv][1] = q; }
  __syncthreads();
  s = ps[0][0] + ps[1][0] + ps[2][0] + ps[3][0];
  q = ps[0][1] + ps[1][1] + ps[2][1] + ps[3][1];
  const float mu = s * (1.f / 2048.f);
  const float inv = rsqrtf((q - s * mu) + 1e-5f);
  const float* b1p = b1 + tid * 8;
  const float* s1p = s1 + tid * 8;
  u32x4 outw;
  #pragma unroll
  for (int j = 0; j < 4; ++j){
    float y0 = b1p[2 * j]     * ((x[2 * j]     - mu) * inv) + s1p[2 * j];
    float y1 = b1p[2 * j + 1] * ((x[2 * j + 1] - mu) * inv) + s1p[2 * j + 1];
    outw[j] = (unsigned int)f2b(y0) | ((unsigned int)f2b(y1) << 16);
  }
  *(u32x4*)rp = outw;
}

// ---------------- Phase 2: persistent recurrence ----------------
__global__ __launch_bounds__(512, 2) void lstm_rec(
    const unsigned short* __restrict__ Gi,   // [32768][2048] bf16, post-LN gi
    const unsigned short* __restrict__ Whb,  // [2048][512] bf16
    const float* __restrict__ bias,
    const float* __restrict__ b2, const float* __restrict__ s2,
    const float* __restrict__ b3, const float* __restrict__ s3,
    const float* __restrict__ hx,            // [64][512] f32 (t=0 h)
    const float* __restrict__ cx,
    unsigned int* __restrict__ hbuf,         // [2][64][512] u32 {o|cc} bf16, UNTAGGED
    unsigned long long* __restrict__ pF,     // [2][4][16] flag u64 = step tag, zeroed
    unsigned long long* __restrict__ pA,     // [2][4][16][32] tagged u64, zeroed
    unsigned long long* __restrict__ pCs,    // [2][4][16][32] tagged u64, zeroed
    float* __restrict__ out){
  const int tid = threadIdx.x;
  const int tm = (blockIdx.x >> 1) & 3;                  // team
  const int ks = ((blockIdx.x >> 3) << 1) | (blockIdx.x & 1);  // slice
  const int w = tid >> 6;
  const int lane = tid & 63;
  const int lr = lane & 15, lq = lane >> 4;

  // gate-wave constants: wave w owns gate rows type*512 + ks*32 + jloc
  const int type = w >> 1;
  const int jloc = (w & 1) * 16 + lr;
  const int row_g = type * 512 + ks * 32 + jloc;
  const float b2r = b2[row_g];
  const float sbr = s2[row_g] + bias[row_g];

  // Wh B-fragments in registers
  bf16x8 bfr[16];
  {
    const unsigned short* wr = Whb + (size_t)row_g * 512 + lq * 8;
    #pragma unroll
    for (int kk = 0; kk < 16; ++kk) bfr[kk] = *(const bf16x8*)(wr + kk * 32);
  }

  // c-phase constants
  const int cs = tid >> 5;                 // team sample 0..15 (== psmp below)
  const int cj = tid & 31;                 // col within slice
  const int hcol = ks * 32 + cj;
  const int bidx = tm * 16 + cs;
  float c_val = cx[(size_t)bidx * 512 + hcol];
  const float b3j = b3[hcol], s3j = s3[hcol];

  // poll coords: wave w covers team samples 2w, 2w+1
  const int psmp = 2 * w + (lane >> 5);    // 0..15 (equals this thread's cs)
  const int pidx = lane & 31;
  const int pl_slice = (lane >> 1) & 15;
  const int pl_kind  = lane & 1;

  // register-cache b3/s3 for reconstruction cols: c = 4*pidx + 128*q + j
  float b3c[16], s3c[16];
  #pragma unroll
  for (int q = 0; q < 4; ++q)
    #pragma unroll
    for (int j = 0; j < 4; ++j){
      const int c = 4 * pidx + 128 * q + j;
      b3c[4 * q + j] = b3[c];
      s3c[4 * q + j] = s3[c];
    }

  __shared__ unsigned short hlds[16 * 520];
  __shared__ float act[4][32][17];
  __shared__ float redA[8][16][2];
  __shared__ float stAl[16][2];

  float cc_own = 0.f, o_own = 0.f;

  for (int t = 0; t < 512; ++t){
    // gi prefetch (in flight during the flag poll)
    float giv[4];
    #pragma unroll
    for (int r = 0; r < 4; ++r){
      const int b = tm * 16 + lq * 4 + r;
      giv[r] = b2f(Gi[((size_t)b * 512 + t) * 2048 + row_g]);
    }

    if (t == 0){
      // read hx directly (kernel argument; ready at launch, no sync needed)
      const float* hr = hx + (size_t)(tm * 16 + psmp) * 512;
      #pragma unroll
      for (int q = 0; q < 4; ++q){
        f32x4 hv4 = *(const f32x4*)(hr + 4 * pidx + 128 * q);
        unsigned long long pk = 0;
        #pragma unroll
        for (int j = 0; j < 4; ++j)
          pk |= (unsigned long long)f2b(hv4[j]) << (16 * j);
        *(unsigned long long*)&hlds[psmp * 520 + 4 * pidx + 128 * q] = pk;
      }
    } else {
      // ---- phase 1: cheap sweep {16 flags + 1 c-stat}, 2 loads/lane ----
      const unsigned int tg = (unsigned)t;
      const unsigned long long* fp = pF + (size_t)(t & 1) * 64 + tm * 16 + (lane & 15);
      const unsigned long long* sp =
          pCs + ((size_t)(t & 1) * 4 + tm) * 512 + pl_slice * 32 + psmp * 2 + pl_kind;
      unsigned long long sv;
      for (;;){
        unsigned long long fv = __hip_atomic_load(fp, __ATOMIC_RELAXED, __HIP_MEMORY_SCOPE_AGENT);
        sv = __hip_atomic_load(sp, __ATOMIC_RELAXED, __HIP_MEMORY_SCOPE_AGENT);
        bool ok = ((unsigned)fv == tg) & ((unsigned)(sv >> 32) == tg);
        if (__all((int)ok)) break;
        __builtin_amdgcn_s_sleep(1);
      }
      // ---- phase 2: read payload ONCE (in flight under the stat reduce) ----
      const unsigned int* hsrc =
          hbuf + (size_t)(t & 1) * 32768 + (size_t)(tm * 16 + psmp) * 512;
      u32x4 pay[4];
      #pragma unroll
      for (int q = 0; q < 4; ++q) LD4_AGENT(pay[q], hsrc + 4 * pidx + 128 * q);
      // c-stats: butterfly over 16 slices, then kind exchange
      float pv = __builtin_bit_cast(float, (unsigned)sv);
      #pragma unroll
      for (int o = 2; o < 32; o <<= 1) pv += __shfl_xor(pv, o);
      const float ov = __shfl_xor(pv, 1);
      const float S = pl_kind ? ov : pv;
      const float Q = pl_kind ? pv : ov;
      const float mu = S * (1.f / 512.f);
      const float inv = rsqrtf((Q - S * mu) + 1e-5f);
      // own carried state + previous step's out row (sample cs == psmp)
      c_val = b3j * ((cc_own - mu) * inv) + s3j;
      const float h_self = o_own * tanh_fast(c_val);
      out[((size_t)bidx * 512 + (t - 1)) * 512 + hcol] = h_self;
      VM0_FENCE();                     // payload arrived
      // reconstruct h(t) for sample psmp: 16 cols per lane
      #pragma unroll
      for (int q = 0; q < 4; ++q){
        unsigned long long pk = 0;
        #pragma unroll
        for (int j = 0; j < 4; ++j){
          const unsigned int v = pay[q][j];
          const float ccv = b2f((unsigned short)(v & 0xFFFF));
          const float oov = b2f((unsigned short)(v >> 16));
          const float h = oov * tanh_fast(b3c[4 * q + j] * ((ccv - mu) * inv) + s3c[4 * q + j]);
          pk |= (unsigned long long)f2b(h) << (16 * j);
        }
        *(unsigned long long*)&hlds[psmp * 520 + 4 * pidx + 128 * q] = pk;
      }
    }
    __syncthreads();                                   // S1

    // A-frags from LDS; MFMA over K=512
    f32x4 acc = {0.f, 0.f, 0.f, 0.f};
    #pragma unroll
    for (int kk = 0; kk < 16; ++kk){
      bf16x8 af = *(const bf16x8*)&hlds[lr * 520 + lq * 8 + kk * 32];
      acc = __builtin_amdgcn_mfma_f32_16x16x32_bf16(af, bfr[kk], acc, 0, 0, 0);
    }
    // per-sample partial (s,q) over this wave's 16 gate cols
    #pragma unroll
    for (int r = 0; r < 4; ++r){
      float s = acc[r], q = acc[r] * acc[r];
      #pragma unroll
      for (int o = 1; o < 16; o <<= 1){ s += __shfl_xor(s, o); q += __shfl_xor(q, o); }
      if (lr == 0){ redA[w][lq * 4 + r][0] = s; redA[w][lq * 4 + r][1] = q; }
    }
    __syncthreads();                                   // S2

    // ---- hop A: tagged partial store + direct all-wave poll ----
    unsigned long long* slotA = pA + ((size_t)(t & 1) * 4 + tm) * 512;  // [16][32] u64
    const unsigned int atag = (unsigned)(t + 1);
    if (w == 0 && lane < 32){
      const int smp = lane >> 1, kd = lane & 1;
      float Sp = 0.f;
      #pragma unroll
      for (int w2 = 0; w2 < 8; ++w2) Sp += redA[w2][smp][kd];
      const unsigned long long pvs = ((unsigned long long)atag << 32) |
          (unsigned long long)__builtin_bit_cast(unsigned int, Sp);
      __hip_atomic_store(slotA + (size_t)ks * 32 + lane, pvs,
                         __ATOMIC_RELAXED, __HIP_MEMORY_SCOPE_AGENT);
    }
    {
      const unsigned long long* ap = slotA + pl_slice * 32 + psmp * 2 + pl_kind;
      unsigned long long av;
      for (;;){
        av = __hip_atomic_load(ap, __ATOMIC_RELAXED, __HIP_MEMORY_SCOPE_AGENT);
        if (__all((int)((unsigned)(av >> 32) == atag))) break;
        __builtin_amdgcn_s_sleep(2);
      }
      float pv = __builtin_bit_cast(float, (unsigned)av);
      #pragma unroll
      for (int o = 2; o < 32; o <<= 1) pv += __shfl_xor(pv, o);  // sum 16 slices
      const float ov = __shfl_xor(pv, 1);
      const float S = pl_kind ? ov : pv;
      const float Q = pl_kind ? pv : ov;
      if ((lane & 31) == 0){
        const float mu = S * (1.f / 2048.f);
        stAl[psmp][0] = mu;
        stAl[psmp][1] = rsqrtf((Q - S * mu) + 1e-5f);
      }
    }
    __syncthreads();                                   // S3

    // gates + activations
    #pragma unroll
    for (int r = 0; r < 4; ++r){
      const int s0 = lq * 4 + r;
      const float nv = (acc[r] - stAl[s0][0]) * stAl[s0][1];
      const float gv = giv[r] + b2r * nv + sbr;
      float a;
      if (type == 2) a = tanh_fast(gv);
      else           a = sigmoid_fast(gv);
      act[type][jloc][s0] = a;
    }
    __syncthreads();                                   // S4

    // c-candidate; post UNTAGGED payload {o|cc} immediately
    const float i_g = act[0][cj][cs];
    const float f_g = act[1][cj][cs];
    const float g_g = act[2][cj][cs];
    const float o_g = act[3][cj][cs];
    const float cc = f_g * c_val + i_g * g_g;
    const unsigned int ntag = (unsigned)(t + 1);
    const size_t np = (size_t)((t + 1) & 1);
    {
      const unsigned int pv32 = (unsigned int)f2b(cc) | ((unsigned int)f2b(o_g) << 16);
      __hip_atomic_store(hbuf + np * 32768 + (size_t)bidx * 512 + hcol, pv32,
                         __ATOMIC_RELAXED, __HIP_MEMORY_SCOPE_AGENT);
    }
    // per-sample c-stats (32-lane in-wave reduce), then post
    float sC = cc, qC = cc * cc;
    #pragma unroll
    for (int o = 1; o < 32; o <<= 1){ sC += __shfl_xor(sC, o); qC += __shfl_xor(qC, o); }
    unsigned long long* slotC = pCs + (np * 4 + tm) * 512;  // [16][32] u64
    if ((lane & 31) < 2){
      const float v = (lane & 1) ? qC : sC;
      const unsigned long long pvs = ((unsigned long long)ntag << 32) |
          (unsigned long long)__builtin_bit_cast(unsigned int, v);
      __hip_atomic_store(slotC + (size_t)ks * 32 + cs * 2 + (lane & 1), pvs,
                         __ATOMIC_RELAXED, __HIP_MEMORY_SCOPE_AGENT);
    }
    // ---- publish: wait own-wave write-acks, wg barrier, ONE flag store ----
    VM0_FENCE();
    __syncthreads();                                   // S5
    if (tid == 0)
      __hip_atomic_store(pF + np * 64 + tm * 16 + ks, (unsigned long long)ntag,
                         __ATOMIC_RELAXED, __HIP_MEMORY_SCOPE_AGENT);
    cc_own = cc; o_own = o_g;
  }

  // epilogue: finish step-511 LN (tag 512, parity 0) and write tail outputs
  {
    const unsigned long long* sp =
        pCs + ((size_t)0 * 4 + tm) * 512 + pl_slice * 32 + psmp * 2 + pl_kind;
    unsigned long long sv;
    for (;;){
      sv = __hip_atomic_load(sp, __ATOMIC_RELAXED, __HIP_MEMORY_SCOPE_AGENT);
      if (__all((int)((unsigned)(sv >> 32) == 512u))) break;
      __builtin_amdgcn_s_sleep(2);
    }
    float pv = __builtin_bit_cast(float, (unsigned)sv);
    #pragma unroll
    for (int o = 2; o < 32; o <<= 1) pv += __shfl_xor(pv, o);
    const float ov = __shfl_xor(pv, 1);
    const float S = pl_kind ? ov : pv;
    const float Q = pl_kind ? pv : ov;
    const float mu = S * (1.f / 512.f);
    const float inv = rsqrtf((Q - S * mu) + 1e-5f);
    const float cn = b3j * ((cc_own - mu) * inv) + s3j;
    const float h = o_own * tanh_fast(cn);
    out[((size_t)bidx * 512 + 511) * 512 + hcol] = h;
    out[16777216u + (size_t)bidx * 512 + hcol] = h;
    out[16777216u + 32768u + (size_t)bidx * 512 + hcol] = cn;
  }
}

extern "C" void kernel_launch(void* const* d_in, const int* in_sizes, int n_in,
                              void* d_out, int out_size, void* d_ws, size_t ws_size,
                              hipStream_t stream){
  (void)in_sizes; (void)n_in; (void)out_size; (void)ws_size;
  const float* x    = (const float*)d_in[0];
  const float* hx   = (const float*)d_in[1];
  const float* cx   = (const float*)d_in[2];
  const float* Wi   = (const float*)d_in[3];
  const float* Wh   = (const float*)d_in[4];
  const float* bias = (const float*)d_in[5];
  const float* b1   = (const float*)d_in[6];
  const float* b2   = (const float*)d_in[7];
  const float* b3   = (const float*)d_in[8];
  const float* s1   = (const float*)d_in[9];
  const float* s2   = (const float*)d_in[10];
  const float* s3   = (const float*)d_in[11];
  float* out = (float*)d_out;
  char* ws = (char*)d_ws;

  unsigned short*     xb   = (unsigned short*)(ws);                 // 33,554,432
  unsigned short*     wib  = (unsigned short*)(ws + 33554432);      //  2,097,152
  unsigned short*     whb  = (unsigned short*)(ws + 35651584);      //  2,097,152
  unsigned short*     gp   = (unsigned short*)(ws + 37748736);      // 134,217,728
  unsigned int*       hbuf = (unsigned int*)(ws + 171966464);       //    262,144  [2][64][512] u32
  unsigned long long* pF   = (unsigned long long*)(ws + 172228608); //      1,024 (region reserved)
  unsigned long long* pA   = (unsigned long long*)(ws + 172490752); //     32,768
  unsigned long long* pCs  = (unsigned long long*)(ws + 172523520); //     32,768

  // zero pF..pCs (contiguous 327,680 B). hbuf needs no init (flag-gated).
  hipMemsetAsync(pF, 0, 327680, stream);
  conv_bf16<<<16384, 256, 0, stream>>>(x,  xb,  4194304);
  conv_bf16<<<1024,  256, 0, stream>>>(Wi, wib, 262144);
  conv_bf16<<<1024,  256, 0, stream>>>(Wh, whb, 262144);
  gemm_gi<<<dim3(256, 16, 1), 256, 0, stream>>>(xb, wib, gp);
  ln_rows<<<32768, 256, 0, stream>>>(gp, b1, s1);
  lstm_rec<<<64, 512, 0, stream>>>(gp, whb, bias, b2, s2, b3, s3, hx, cx,
                                   hbuf, pF, pA, pCs, out);
}

// Round 11
// 3089.561 us; speedup vs baseline: 1.2513x; 1.0525x over previous
//
#include <hip/hip_runtime.h>
#include <cstdint>
#include <cstddef>

// LayerNormLSTM on MI355X.
// Phase 0: fp32->bf16 conversion of x, Wi, Wh.
// Phase 1: Gpre = x @ Wi^T  (bf16 MFMA 16x16x32, 128x128 tiles).
// Phase 1.5: in-place row LN (scale=b1, shift=s1) over the 2048 gate dim.
// Phase 2: persistent recurrence, 64 wgs = 4 teams(16 samples) x 16 slices.
//   R14 = R13/R8 protocol with OFFSET-PIPELINED POLLS: the two critical
//   polls (flag+c-stat sweep; hop-A stats) keep TWO load-batches in flight,
//   issued ~0.35us apart, checked alternately via s_waitcnt vmcnt(2)/(1).
//   Memory is sampled every ~0.45us instead of ~0.93us (the serial
//   load-latency self-clock of the old loop). vmcnt rotation is
//   prior-load-count-agnostic: vmcnt(K) <=> only the newest batch (K loads)
//   outstanding <=> the checked batch landed. On success the other batch's
//   pending loads are NOT drained; their registers are liveness-pinned past
//   the next existing vmcnt(0) fence (payload fence / pre-S5 fence) which
//   subsumes the drain for free. sched_barrier(0) after every waitcnt so
//   register-only tag compares cannot hoist above it (rule #18).

typedef float  f32x4 __attribute__((ext_vector_type(4)));
typedef __bf16 bf16x8 __attribute__((ext_vector_type(8)));
typedef unsigned int u32x4 __attribute__((ext_vector_type(4)));
typedef unsigned short u16x4 __attribute__((ext_vector_type(4)));

#define DEV __device__ __forceinline__

// agent-scope (MALL) loads, untracked by compiler -> manual waitcnt
#define LD4_AGENT(dst, p) asm volatile("global_load_dwordx4 %0, %1, off sc1" : "=v"(dst) : "v"(p) : "memory")
#define ISSUE_U64(dst, p) asm volatile("global_load_dwordx2 %0, %1, off sc1" : "=v"(dst) : "v"(p) : "memory")
#define WAIT_VM(N) do{ asm volatile("s_waitcnt vmcnt(" #N ")" ::: "memory"); \
                       __builtin_amdgcn_sched_barrier(0);}while(0)
#define VM0_FENCE() do{ asm volatile("s_waitcnt vmcnt(0)" ::: "memory"); \
                        __builtin_amdgcn_sched_barrier(0); }while(0)

DEV unsigned short f2b(float f){
  unsigned int u = __builtin_bit_cast(unsigned int, f);
  unsigned int r = (u + 0x7FFFu + ((u >> 16) & 1u)) >> 16;
  return (unsigned short)r;
}
DEV float b2f(unsigned short s){
  unsigned int u = ((unsigned int)s) << 16;
  return __builtin_bit_cast(float, u);
}
DEV float tanh_fast(float x){
  const float e = __expf(2.f * x);
  return 1.f - 2.f * __builtin_amdgcn_rcpf(e + 1.f);
}
DEV float sigmoid_fast(float x){
  return __builtin_amdgcn_rcpf(1.f + __expf(-x));
}

// ---------------- Phase 0: conversion ----------------
__global__ __launch_bounds__(256) void conv_bf16(const float* __restrict__ src,
                                                 unsigned short* __restrict__ dst,
                                                 int n4){
  int i = blockIdx.x * 256 + threadIdx.x;
  if (i >= n4) return;
  f32x4 v = ((const f32x4*)src)[i];
  u16x4 o;
  #pragma unroll
  for (int j = 0; j < 4; ++j) o[j] = f2b(v[j]);
  ((u16x4*)dst)[i] = o;
}

// ---------------- Phase 1: Gpre = Xb @ Wib^T ----------------
__global__ __launch_bounds__(256, 2) void gemm_gi(const unsigned short* __restrict__ Xb,
                                                  const unsigned short* __restrict__ Wib,
                                                  unsigned short* __restrict__ Gp){
  __shared__ unsigned short As[128 * 48];
  __shared__ unsigned short Bs[128 * 48];
  const int tid = threadIdx.x;
  const int m0 = blockIdx.x * 128;
  const int n0 = blockIdx.y * 128;
  const int w = tid >> 6, lane = tid & 63;
  const int lr = lane & 15, lq = lane >> 4;
  const int wm = (w & 1) * 64, wn = (w >> 1) * 64;
  const int sr = tid >> 2;
  const int sc = (tid & 3) * 8;
  const unsigned short* gx = Xb + (size_t)(m0 + sr) * 512 + sc;
  const unsigned short* gw = Wib + (size_t)(n0 + sr) * 512 + sc;
  f32x4 acc[4][4] = {};
  for (int kb = 0; kb < 16; ++kb){
    u32x4 a0 = *(const u32x4*)(gx + kb * 32);
    u32x4 a1 = *(const u32x4*)(gx + 64 * 512 + kb * 32);
    u32x4 b0 = *(const u32x4*)(gw + kb * 32);
    u32x4 b1 = *(const u32x4*)(gw + 64 * 512 + kb * 32);
    __syncthreads();
    *(u32x4*)&As[sr * 48 + sc] = a0;
    *(u32x4*)&As[(sr + 64) * 48 + sc] = a1;
    *(u32x4*)&Bs[sr * 48 + sc] = b0;
    *(u32x4*)&Bs[(sr + 64) * 48 + sc] = b1;
    __syncthreads();
    bf16x8 af[4], bfv[4];
    #pragma unroll
    for (int mi = 0; mi < 4; ++mi) af[mi] = *(const bf16x8*)&As[(wm + mi * 16 + lr) * 48 + lq * 8];
    #pragma unroll
    for (int ni = 0; ni < 4; ++ni) bfv[ni] = *(const bf16x8*)&Bs[(wn + ni * 16 + lr) * 48 + lq * 8];
    #pragma unroll
    for (int mi = 0; mi < 4; ++mi)
      #pragma unroll
      for (int ni = 0; ni < 4; ++ni)
        acc[mi][ni] = __builtin_amdgcn_mfma_f32_16x16x32_bf16(af[mi], bfv[ni], acc[mi][ni], 0, 0, 0);
  }
  #pragma unroll
  for (int mi = 0; mi < 4; ++mi){
    const int rowb = m0 + wm + mi * 16 + lq * 4;
    #pragma unroll
    for (int ni = 0; ni < 4; ++ni){
      const int col = n0 + wn + ni * 16 + lr;
      #pragma unroll
      for (int r = 0; r < 4; ++r)
        Gp[(size_t)(rowb + r) * 2048 + col] = f2b(acc[mi][ni][r]);
    }
  }
}

// ---------------- Phase 1.5: row LN (scale=b1, shift=s1) ----------------
__global__ __launch_bounds__(256) void ln_rows(unsigned short* __restrict__ G,
                                               const float* __restrict__ b1,
                                               const float* __restrict__ s1){
  const int row = blockIdx.x;
  const int tid = threadIdx.x;
  unsigned short* rp = G + (size_t)row * 2048 + tid * 8;
  u32x4 raw = *(const u32x4*)rp;
  float x[8];
  #pragma unroll
  for (int j = 0; j < 8; ++j){
    unsigned int word = raw[j >> 1];
    unsigned short us = (j & 1) ? (unsigned short)(word >> 16) : (unsigned short)(word & 0xFFFF);
    x[j] = b2f(us);
  }
  float s = 0.f, q = 0.f;
  #pragma unroll
  for (int j = 0; j < 8; ++j){ s += x[j]; q += x[j] * x[j]; }
  #pragma unroll
  for (int o = 1; o < 64; o <<= 1){ s += __shfl_xor(s, o); q += __shfl_xor(q, o); }
  __shared__ float ps[4][2];
  const int wv = tid >> 6;
  if ((tid & 63) == 0){ ps[wv][0] = s; ps[wv][1] = q; }
  __syncthreads();
  s = ps[0][0] + ps[1][0] + ps[2][0] + ps[3][0];
  q = ps[0][1] + ps[1][1] + ps[2][1] + ps[3][1];
  const float mu = s * (1.f / 2048.f);
  const float inv = rsqrtf((q - s * mu) + 1e-5f);
  const float* b1p = b1 + tid * 8;
  const float* s1p = s1 + tid * 8;
  u32x4 outw;
  #pragma unroll
  for (int j = 0; j < 4; ++j){
    float y0 = b1p[2 * j]     * ((x[2 * j]     - mu) * inv) + s1p[2 * j];
    float y1 = b1p[2 * j + 1] * ((x[2 * j + 1] - mu) * inv) + s1p[2 * j + 1];
    outw[j] = (unsigned int)f2b(y0) | ((unsigned int)f2b(y1) << 16);
  }
  *(u32x4*)rp = outw;
}

// ---------------- Phase 2: persistent recurrence ----------------
__global__ __launch_bounds__(512, 2) void lstm_rec(
    const unsigned short* __restrict__ Gi,   // [32768][2048] bf16, post-LN gi
    const unsigned short* __restrict__ Whb,  // [2048][512] bf16
    const float* __restrict__ bias,
    const float* __restrict__ b2, const float* __restrict__ s2,
    const float* __restrict__ b3, const float* __restrict__ s3,
    const float* __restrict__ hx,            // [64][512] f32 (t=0 h)
    const float* __restrict__ cx,
    unsigned int* __restrict__ hbuf,         // [2][64][512] u32 {o|cc} bf16, UNTAGGED
    unsigned long long* __restrict__ pF,     // [2][4][16] flag u64 = step tag, zeroed
    unsigned long long* __restrict__ pA,     // [2][4][16][32] tagged u64, zeroed
    unsigned long long* __restrict__ pCs,    // [2][4][16][32] tagged u64, zeroed
    float* __restrict__ out){
  const int tid = threadIdx.x;
  const int tm = (blockIdx.x >> 1) & 3;                  // team
  const int ks = ((blockIdx.x >> 3) << 1) | (blockIdx.x & 1);  // slice
  const int w = tid >> 6;
  const int lane = tid & 63;
  const int lr = lane & 15, lq = lane >> 4;

  // gate-wave constants: wave w owns gate rows type*512 + ks*32 + jloc
  const int type = w >> 1;
  const int jloc = (w & 1) * 16 + lr;
  const int row_g = type * 512 + ks * 32 + jloc;
  const float b2r = b2[row_g];
  const float sbr = s2[row_g] + bias[row_g];

  // Wh B-fragments in registers
  bf16x8 bfr[16];
  {
    const unsigned short* wr = Whb + (size_t)row_g * 512 + lq * 8;
    #pragma unroll
    for (int kk = 0; kk < 16; ++kk) bfr[kk] = *(const bf16x8*)(wr + kk * 32);
  }

  // c-phase constants
  const int cs = tid >> 5;                 // team sample 0..15 (== psmp below)
  const int cj = tid & 31;                 // col within slice
  const int hcol = ks * 32 + cj;
  const int bidx = tm * 16 + cs;
  float c_val = cx[(size_t)bidx * 512 + hcol];
  const float b3j = b3[hcol], s3j = s3[hcol];

  // poll coords: wave w covers team samples 2w, 2w+1
  const int psmp = 2 * w + (lane >> 5);    // 0..15 (equals this thread's cs)
  const int pidx = lane & 31;
  const int pl_slice = (lane >> 1) & 15;
  const int pl_kind  = lane & 1;

  // register-cache b3/s3 for reconstruction cols: c = 4*pidx + 128*q + j
  float b3c[16], s3c[16];
  #pragma unroll
  for (int q = 0; q < 4; ++q)
    #pragma unroll
    for (int j = 0; j < 4; ++j){
      const int c = 4 * pidx + 128 * q + j;
      b3c[4 * q + j] = b3[c];
      s3c[4 * q + j] = s3[c];
    }

  __shared__ unsigned short hlds[16 * 520];
  __shared__ float act[4][32][17];
  __shared__ float redA[8][16][2];
  __shared__ float stAl[16][2];

  float cc_own = 0.f, o_own = 0.f;

  for (int t = 0; t < 512; ++t){
    // gi prefetch (in flight during the flag poll)
    float giv[4];
    #pragma unroll
    for (int r = 0; r < 4; ++r){
      const int b = tm * 16 + lq * 4 + r;
      giv[r] = b2f(Gi[((size_t)b * 512 + t) * 2048 + row_g]);
    }

    if (t == 0){
      // read hx directly (kernel argument; ready at launch, no sync needed)
      const float* hr = hx + (size_t)(tm * 16 + psmp) * 512;
      #pragma unroll
      for (int q = 0; q < 4; ++q){
        f32x4 hv4 = *(const f32x4*)(hr + 4 * pidx + 128 * q);
        unsigned long long pk = 0;
        #pragma unroll
        for (int j = 0; j < 4; ++j)
          pk |= (unsigned long long)f2b(hv4[j]) << (16 * j);
        *(unsigned long long*)&hlds[psmp * 520 + 4 * pidx + 128 * q] = pk;
      }
    } else {
      // ---- phase 1: offset-pipelined sweep {16 flags + 1 c-stat} ----
      const unsigned int tg = (unsigned)t;
      const unsigned long long* fp = pF + (size_t)(t & 1) * 64 + tm * 16 + (lane & 15);
      const unsigned long long* sp =
          pCs + ((size_t)(t & 1) * 4 + tm) * 512 + pl_slice * 32 + psmp * 2 + pl_kind;
      unsigned long long fa, sa, fb, sb;
      unsigned long long sv;
      ISSUE_U64(fa, fp); ISSUE_U64(sa, sp);
      __builtin_amdgcn_s_sleep(12);          // ~0.33us issue offset
      ISSUE_U64(fb, fp); ISSUE_U64(sb, sp);
      for (;;){
        WAIT_VM(2);                          // batch A landed (B outstanding)
        bool ok = ((unsigned)fa == tg) & ((unsigned)(sa >> 32) == tg);
        if (__all((int)ok)){ sv = sa; break; }
        ISSUE_U64(fa, fp); ISSUE_U64(sa, sp);
        WAIT_VM(2);                          // batch B landed (A outstanding)
        ok = ((unsigned)fb == tg) & ((unsigned)(sb >> 32) == tg);
        if (__all((int)ok)){ sv = sb; break; }
        ISSUE_U64(fb, fp); ISSUE_U64(sb, sp);
      }
      // up to 2 loads of the other batch still in flight; drained by the
      // payload VM0_FENCE below. Registers pinned after that fence.
      // ---- phase 2: read payload ONCE (in flight under the stat reduce) ----
      const unsigned int* hsrc =
          hbuf + (size_t)(t & 1) * 32768 + (size_t)(tm * 16 + psmp) * 512;
      u32x4 pay[4];
      #pragma unroll
      for (int q = 0; q < 4; ++q) LD4_AGENT(pay[q], hsrc + 4 * pidx + 128 * q);
      // c-stats: butterfly over 16 slices, then kind exchange
      float pv = __builtin_bit_cast(float, (unsigned)sv);
      #pragma unroll
      for (int o = 2; o < 32; o <<= 1) pv += __shfl_xor(pv, o);
      const float ov = __shfl_xor(pv, 1);
      const float S = pl_kind ? ov : pv;
      const float Q = pl_kind ? pv : ov;
      const float mu = S * (1.f / 512.f);
      const float inv = rsqrtf((Q - S * mu) + 1e-5f);
      // own carried state + previous step's out row (sample cs == psmp)
      c_val = b3j * ((cc_own - mu) * inv) + s3j;
      const float h_self = o_own * tanh_fast(c_val);
      out[((size_t)bidx * 512 + (t - 1)) * 512 + hcol] = h_self;
      VM0_FENCE();                     // payload + stale poll batch drained
      asm volatile("" :: "v"(fa), "v"(sa), "v"(fb), "v"(sb));  // liveness pin
      // reconstruct h(t) for sample psmp: 16 cols per lane
      #pragma unroll
      for (int q = 0; q < 4; ++q){
        unsigned long long pk = 0;
        #pragma unroll
        for (int j = 0; j < 4; ++j){
          const unsigned int v = pay[q][j];
          const float ccv = b2f((unsigned short)(v & 0xFFFF));
          const float oov = b2f((unsigned short)(v >> 16));
          const float h = oov * tanh_fast(b3c[4 * q + j] * ((ccv - mu) * inv) + s3c[4 * q + j]);
          pk |= (unsigned long long)f2b(h) << (16 * j);
        }
        *(unsigned long long*)&hlds[psmp * 520 + 4 * pidx + 128 * q] = pk;
      }
    }
    __syncthreads();                                   // S1

    // A-frags from LDS; MFMA over K=512
    f32x4 acc = {0.f, 0.f, 0.f, 0.f};
    #pragma unroll
    for (int kk = 0; kk < 16; ++kk){
      bf16x8 af = *(const bf16x8*)&hlds[lr * 520 + lq * 8 + kk * 32];
      acc = __builtin_amdgcn_mfma_f32_16x16x32_bf16(af, bfr[kk], acc, 0, 0, 0);
    }
    // per-sample partial (s,q) over this wave's 16 gate cols
    #pragma unroll
    for (int r = 0; r < 4; ++r){
      float s = acc[r], q = acc[r] * acc[r];
      #pragma unroll
      for (int o = 1; o < 16; o <<= 1){ s += __shfl_xor(s, o); q += __shfl_xor(q, o); }
      if (lr == 0){ redA[w][lq * 4 + r][0] = s; redA[w][lq * 4 + r][1] = q; }
    }
    __syncthreads();                                   // S2

    // ---- hop A: tagged partial store + offset-pipelined all-wave poll ----
    unsigned long long* slotA = pA + ((size_t)(t & 1) * 4 + tm) * 512;  // [16][32] u64
    const unsigned int atag = (unsigned)(t + 1);
    if (w == 0 && lane < 32){
      const int smp = lane >> 1, kd = lane & 1;
      float Sp = 0.f;
      #pragma unroll
      for (int w2 = 0; w2 < 8; ++w2) Sp += redA[w2][smp][kd];
      const unsigned long long pvs = ((unsigned long long)atag << 32) |
          (unsigned long long)__builtin_bit_cast(unsigned int, Sp);
      __hip_atomic_store(slotA + (size_t)ks * 32 + lane, pvs,
                         __ATOMIC_RELAXED, __HIP_MEMORY_SCOPE_AGENT);
    }
    unsigned long long aa, ab;
    {
      const unsigned long long* ap = slotA + pl_slice * 32 + psmp * 2 + pl_kind;
      unsigned long long av;
      ISSUE_U64(aa, ap);
      __builtin_amdgcn_s_sleep(12);
      ISSUE_U64(ab, ap);
      for (;;){
        WAIT_VM(1);                          // aa landed (ab outstanding)
        if (__all((int)((unsigned)(aa >> 32) == atag))){ av = aa; break; }
        ISSUE_U64(aa, ap);
        WAIT_VM(1);                          // ab landed (aa outstanding)
        if (__all((int)((unsigned)(ab >> 32) == atag))){ av = ab; break; }
        ISSUE_U64(ab, ap);
      }
      // 1 load may remain in flight; drained at the pre-S5 VM0_FENCE.
      float pv = __builtin_bit_cast(float, (unsigned)av);
      #pragma unroll
      for (int o = 2; o < 32; o <<= 1) pv += __shfl_xor(pv, o);  // sum 16 slices
      const float ov = __shfl_xor(pv, 1);
      const float S = pl_kind ? ov : pv;
      const float Q = pl_kind ? pv : ov;
      if ((lane & 31) == 0){
        const float mu = S * (1.f / 2048.f);
        stAl[psmp][0] = mu;
        stAl[psmp][1] = rsqrtf((Q - S * mu) + 1e-5f);
      }
    }
    __syncthreads();                                   // S3

    // gates + activations
    #pragma unroll
    for (int r = 0; r < 4; ++r){
      const int s0 = lq * 4 + r;
      const float nv = (acc[r] - stAl[s0][0]) * stAl[s0][1];
      const float gv = giv[r] + b2r * nv + sbr;
      float a;
      if (type == 2) a = tanh_fast(gv);
      else           a = sigmoid_fast(gv);
      act[type][jloc][s0] = a;
    }
    __syncthreads();                                   // S4

    // c-candidate; post UNTAGGED payload {o|cc} immediately
    const float i_g = act[0][cj][cs];
    const float f_g = act[1][cj][cs];
    const float g_g = act[2][cj][cs];
    const float o_g = act[3][cj][cs];
    const float cc = f_g * c_val + i_g * g_g;
    const unsigned int ntag = (unsigned)(t + 1);
    const size_t np = (size_t)((t + 1) & 1);
    {
      const unsigned int pv32 = (unsigned int)f2b(cc) | ((unsigned int)f2b(o_g) << 16);
      __hip_atomic_store(hbuf + np * 32768 + (size_t)bidx * 512 + hcol, pv32,
                         __ATOMIC_RELAXED, __HIP_MEMORY_SCOPE_AGENT);
    }
    // per-sample c-stats (32-lane in-wave reduce), then post
    float sC = cc, qC = cc * cc;
    #pragma unroll
    for (int o = 1; o < 32; o <<= 1){ sC += __shfl_xor(sC, o); qC += __shfl_xor(qC, o); }
    unsigned long long* slotC = pCs + (np * 4 + tm) * 512;  // [16][32] u64
    if ((lane & 31) < 2){
      const float v = (lane & 1) ? qC : sC;
      const unsigned long long pvs = ((unsigned long long)ntag << 32) |
          (unsigned long long)__builtin_bit_cast(unsigned int, v);
      __hip_atomic_store(slotC + (size_t)ks * 32 + cs * 2 + (lane & 1), pvs,
                         __ATOMIC_RELAXED, __HIP_MEMORY_SCOPE_AGENT);
    }
    // ---- publish: wait own-wave write-acks, wg barrier, ONE flag store ----
    VM0_FENCE();                       // also drains stale hop-A poll load
    asm volatile("" :: "v"(aa), "v"(ab));               // liveness pin
    __syncthreads();                                   // S5
    if (tid == 0)
      __hip_atomic_store(pF + np * 64 + tm * 16 + ks, (unsigned long long)ntag,
                         __ATOMIC_RELAXED, __HIP_MEMORY_SCOPE_AGENT);
    cc_own = cc; o_own = o_g;
  }

  // epilogue: finish step-511 LN (tag 512, parity 0) and write tail outputs
  {
    const unsigned long long* sp =
        pCs + ((size_t)0 * 4 + tm) * 512 + pl_slice * 32 + psmp * 2 + pl_kind;
    unsigned long long sv;
    for (;;){
      sv = __hip_atomic_load(sp, __ATOMIC_RELAXED, __HIP_MEMORY_SCOPE_AGENT);
      if (__all((int)((unsigned)(sv >> 32) == 512u))) break;
      __builtin_amdgcn_s_sleep(2);
    }
    float pv = __builtin_bit_cast(float, (unsigned)sv);
    #pragma unroll
    for (int o = 2; o < 32; o <<= 1) pv += __shfl_xor(pv, o);
    const float ov = __shfl_xor(pv, 1);
    const float S = pl_kind ? ov : pv;
    const float Q = pl_kind ? pv : ov;
    const float mu = S * (1.f / 512.f);
    const float inv = rsqrtf((Q - S * mu) + 1e-5f);
    const float cn = b3j * ((cc_own - mu) * inv) + s3j;
    const float h = o_own * tanh_fast(cn);
    out[((size_t)bidx * 512 + 511) * 512 + hcol] = h;
    out[16777216u + (size_t)bidx * 512 + hcol] = h;
    out[16777216u + 32768u + (size_t)bidx * 512 + hcol] = cn;
  }
}

extern "C" void kernel_launch(void* const* d_in, const int* in_sizes, int n_in,
                              void* d_out, int out_size, void* d_ws, size_t ws_size,
                              hipStream_t stream){
  (void)in_sizes; (void)n_in; (void)out_size; (void)ws_size;
  const float* x    = (const float*)d_in[0];
  const float* hx   = (const float*)d_in[1];
  const float* cx   = (const float*)d_in[2];
  const float* Wi   = (const float*)d_in[3];
  const float* Wh   = (const float*)d_in[4];
  const float* bias = (const float*)d_in[5];
  const float* b1   = (const float*)d_in[6];
  const float* b2   = (const float*)d_in[7];
  const float* b3   = (const float*)d_in[8];
  const float* s1   = (const float*)d_in[9];
  const float* s2   = (const float*)d_in[10];
  const float* s3   = (const float*)d_in[11];
  float* out = (float*)d_out;
  char* ws = (char*)d_ws;

  unsigned short*     xb   = (unsigned short*)(ws);                 // 33,554,432
  unsigned short*     wib  = (unsigned short*)(ws + 33554432);      //  2,097,152
  unsigned short*     whb  = (unsigned short*)(ws + 35651584);      //  2,097,152
  unsigned short*     gp   = (unsigned short*)(ws + 37748736);      // 134,217,728
  unsigned int*       hbuf = (unsigned int*)(ws + 171966464);       //    262,144  [2][64][512] u32
  unsigned long long* pF   = (unsigned long long*)(ws + 172228608); //      1,024 (region reserved)
  unsigned long long* pA   = (unsigned long long*)(ws + 172490752); //     32,768
  unsigned long long* pCs  = (unsigned long long*)(ws + 172523520); //     32,768

  // zero pF..pCs (contiguous 327,680 B). hbuf needs no init (flag-gated).
  hipMemsetAsync(pF, 0, 327680, stream);
  conv_bf16<<<16384, 256, 0, stream>>>(x,  xb,  4194304);
  conv_bf16<<<1024,  256, 0, stream>>>(Wi, wib, 262144);
  conv_bf16<<<1024,  256, 0, stream>>>(Wh, whb, 262144);
  gemm_gi<<<dim3(256, 16, 1), 256, 0, stream>>>(xb, wib, gp);
  ln_rows<<<32768, 256, 0, stream>>>(gp, b1, s1);
  lstm_rec<<<64, 512, 0, stream>>>(gp, whb, bias, b2, s2, b3, s3, hx, cx,
                                   hbuf, pF, pA, pCs, out);
}